// Round 5
// baseline (510.702 us; speedup 1.0000x reference)
//
#include <hip/hip_runtime.h>
#include <hip/hip_bf16.h>

#define N_NODES 50000
#define N_EDGES 1600000
#define IN_F 64
#define E_F 32
#define HID 128
#define OUT_F 4

typedef __attribute__((ext_vector_type(4))) float f32x4;
typedef __attribute__((ext_vector_type(8))) short short8;
typedef __attribute__((ext_vector_type(4))) int i32x4;

__device__ inline short f2bf(float f) {
  union { float f; unsigned u; } v; v.f = f;
  unsigned r = v.u + 0x7FFFu + ((v.u >> 16) & 1u);   // round-to-nearest-even
  return (short)(r >> 16);
}
__device__ inline float bf2f(short s) {
  union { unsigned u; float f; } v; v.u = ((unsigned)(unsigned short)s) << 16;
  return v.f;
}

// -----------------------------------------------------------------------------
// Kernel 1: P[n] = bf16([h[n]@Wu ; h[n]@Wv]), stored per node as
//   [half][col][t]  (256 shorts = 512 B/node), where math feature
//   j = t*16 + col is the hid index. This transpose makes the edge kernel's
//   per-lane gather of its 8 t-slab values one contiguous short8 (16 B) load.
// Thread o = tid&127 owns storage offset o = col*8+t -> feature j(o) =
//   (o&7)*16 + (o>>3). W is staged into LDS pre-permuted so the k-loop read
//   Wl[k*128+o] is conflict-free (o consecutive across the wave).
// -----------------------------------------------------------------------------
__global__ __launch_bounds__(256) void node_pre(const float* __restrict__ h,
                                                const float* __restrict__ W1,
                                                short* __restrict__ P) {
  __shared__ float Wl[128 * 128];     // 64 KiB, permuted: Wl[k*128+o] = W[k][j(o)]
  __shared__ float hl[4][64];
  const int tid = threadIdx.x;
  for (int i = tid; i < 128 * 128; i += 256) {
    const int k = i >> 7, j = i & 127;
    Wl[k * 128 + ((j & 15) * 8 + (j >> 4))] = W1[i];   // one-time 8-way conflict, negligible
  }

  const int o    = tid & 127;         // storage offset within half
  const int half = tid >> 7;          // 0 = u-part, 1 = v-part

  int n0 = blockIdx.x * 98;
  int n1 = min(n0 + 98, N_NODES);
  __syncthreads();

  for (int nb = n0; nb < n1; nb += 4) {
    const int nn = min(4, n1 - nb);
    __syncthreads();                  // previous iter finished reading hl
    {
      const int m = tid >> 6, k = tid & 63;
      if (m < nn) hl[m][k] = h[(nb + m) * IN_F + k];
    }
    __syncthreads();
    float acc[4] = {0.f, 0.f, 0.f, 0.f};
#pragma unroll
    for (int k = 0; k < 64; ++k) {
      const float w = Wl[(half * 64 + k) * 128 + o];   // 2-way across wave: free
#pragma unroll
      for (int m = 0; m < 4; ++m) acc[m] = fmaf(hl[m][k], w, acc[m]);
    }
#pragma unroll
    for (int m = 0; m < 4; ++m)                        // 512 B contiguous burst/node
      if (m < nn) P[(size_t)(nb + m) * 256 + half * 128 + o] = f2bf(acc[m]);
  }
}

// -----------------------------------------------------------------------------
// Kernel 2: fused edge MLP.
//   Per block: 8 tiles of 64 edges (4 waves x 16 edges).
//   e@We via one mfma_f32_16x16x32_bf16 per 16-feat slab (K=32 in one MFMA).
//   D layout (m89-verified): col = lane&15, row = (lane>>4)*4 + reg.
//   A frag: row = lane&15, k = 8*(lane>>4)+i ; B frag: col = lane&15, same k.
//   P gathers: one short8 (16 B) per edge-endpoint-half thanks to the
//   [half][col][t] P layout. ef/src/dst/out streamed nontemporal so the
//   25.6 MB P table keeps L2/L3 residency (gather locality dominates).
// -----------------------------------------------------------------------------
#define TPB 8
__global__ __launch_bounds__(256) void edge_mlp(
    const float* __restrict__ ef, const int* __restrict__ src,
    const int* __restrict__ dst, const float* __restrict__ W1,
    const float* __restrict__ b1, const float* __restrict__ W2,
    const float* __restrict__ b2, const short* __restrict__ P,
    float* __restrict__ out) {
  __shared__ __align__(16) short Elds[64 * 32];   // 64-edge tile, bf16

  const int tid  = threadIdx.x;
  const int lane = tid & 63;
  const int wid  = tid >> 6;
  const int col  = lane & 15;     // feat (N) index within 16-slab
  const int rowg = lane >> 4;     // row group / k group

  // ---- loop-invariant register state ----
  short8 bfrag[8];                // We (32x128) bf16 B-fragments, one per 16-feat slab
#pragma unroll
  for (int t = 0; t < 8; ++t) {
#pragma unroll
    for (int i = 0; i < 8; ++i) {
      const float f = W1[(2 * IN_F + rowg * 8 + i) * HID + t * 16 + col];
      bfrag[t][i] = f2bf(f);
    }
  }
  float b1r[8];
  f32x4 w2r[8];
#pragma unroll
  for (int t = 0; t < 8; ++t) {
    b1r[t] = b1[t * 16 + col];
    w2r[t] = ((const f32x4*)W2)[t * 16 + col];   // W2 row (4 floats)
  }
  const f32x4 b2r = *((const f32x4*)b2);

  for (int tt = 0; tt < TPB; ++tt) {
    const int e0 = (blockIdx.x * TPB + tt) * 64;

    // ---- per-lane edge indices for this tile (issued early) ----
    const int ebase = e0 + wid * 16 + rowg * 4;
    const i32x4 se = __builtin_nontemporal_load((const i32x4*)(src + ebase));
    const i32x4 de = __builtin_nontemporal_load((const i32x4*)(dst + ebase));

    // ---- stage 64x32 e-tile as bf16 into LDS (coalesced float4 loads) ----
    const f32x4* efv = (const f32x4*)(ef + (size_t)e0 * E_F);
    const f32x4 a0 = __builtin_nontemporal_load(efv + tid * 2);
    const f32x4 a1 = __builtin_nontemporal_load(efv + tid * 2 + 1);
    short8 pk;
#pragma unroll
    for (int i = 0; i < 4; ++i) pk[i] = f2bf(a0[i]);
#pragma unroll
    for (int i = 0; i < 4; ++i) pk[4 + i] = f2bf(a1[i]);
    __syncthreads();                       // prev iter done reading Elds
    ((short8*)Elds)[tid] = pk;
    __syncthreads();

    // ---- A fragment + 8 MFMAs: acc[t][q] = (E @ We)[edge row, feat col] ----
    const short8 af = ((short8*)Elds)[(wid * 16 + col) * 4 + rowg];
    f32x4 acc[8];
#pragma unroll
    for (int t = 0; t < 8; ++t)
      acc[t] = __builtin_amdgcn_mfma_f32_16x16x32_bf16(
          af, bfrag[t], (f32x4){0.f, 0.f, 0.f, 0.f}, 0, 0, 0);

    // ---- gather P rows (one short8 per endpoint-half), hid, relu, project ----
    const int sidx[4] = {se.x, se.y, se.z, se.w};
    const int didx[4] = {de.x, de.y, de.z, de.w};
    short8 lu[4], lv[4];
#pragma unroll
    for (int q = 0; q < 4; ++q) {          // issue all 8 gathers before consuming
      lu[q] = *(const short8*)(P + (size_t)sidx[q] * 256 + col * 8);
      lv[q] = *(const short8*)(P + (size_t)didx[q] * 256 + 128 + col * 8);
    }
    f32x4 part[4] = {(f32x4){0,0,0,0}, (f32x4){0,0,0,0},
                     (f32x4){0,0,0,0}, (f32x4){0,0,0,0}};
#pragma unroll
    for (int q = 0; q < 4; ++q) {
#pragma unroll
      for (int t = 0; t < 8; ++t) {
        float hid = acc[t][q] + bf2f(lu[q][t]) + bf2f(lv[q][t]) + b1r[t];
        hid = fmaxf(hid, 0.f);
#pragma unroll
        for (int o = 0; o < 4; ++o)
          part[q][o] = fmaf(hid, w2r[t][o], part[q][o]);
      }
    }

    // ---- reduce over the 16 col-lanes (xor<16 keeps rowg groups intact) ----
#pragma unroll
    for (int q = 0; q < 4; ++q) {
#pragma unroll
      for (int o = 0; o < 4; ++o) {
        float v = part[q][o];
        v += __shfl_xor(v, 1);
        v += __shfl_xor(v, 2);
        v += __shfl_xor(v, 4);
        v += __shfl_xor(v, 8);
        part[q][o] = v + b2r[o];
      }
    }
    if (col == 0) {
#pragma unroll
      for (int q = 0; q < 4; ++q)
        __builtin_nontemporal_store(part[q], (f32x4*)out + ebase + q);
    }
  }
}

extern "C" void kernel_launch(void* const* d_in, const int* in_sizes, int n_in,
                              void* d_out, int out_size, void* d_ws, size_t ws_size,
                              hipStream_t stream) {
  const float* h   = (const float*)d_in[0];
  const float* ef  = (const float*)d_in[1];
  const int*   src = (const int*)d_in[2];
  const int*   dst = (const int*)d_in[3];
  const float* W1  = (const float*)d_in[4];
  const float* b1  = (const float*)d_in[5];
  const float* W2  = (const float*)d_in[6];
  const float* b2  = (const float*)d_in[7];
  float* out = (float*)d_out;
  short* P   = (short*)d_ws;     // 50000 * 256 * 2 B = 25.6 MB scratch

  hipLaunchKernelGGL(node_pre, dim3(512), dim3(256), 0, stream, h, W1, P);
  hipLaunchKernelGGL(edge_mlp, dim3(N_EDGES / (64 * TPB)), dim3(256), 0, stream,
                     ef, src, dst, W1, b1, W2, b2, P, out);
}